// Round 9
// baseline (79.042 us; speedup 1.0000x reference)
//
#include <hip/hip_runtime.h>
#include <stdint.h>

// SWF2LUT 4-simplex interpolation, mode 's'.
// img_in: (8,1,513,513) f32, integer values 0..255
// weight: (17^4, 3) f32  -> quantized clip(round(w*127),-127,127)
// out:    (8,1,512,512,3) f32
//
// Round-9: round 8's fused kernel was a serialization soup: 83.5 KiB LDS ->
// 1 WG/CU, so fill/barrier phases and gather/VALU phases could not overlap
// (only 4 waves/SIMD). Shrink the LDS plane to 80 KiB (81,920 entries) ->
// exactly 2 WGs/CU (32 waves/CU); the 1,586-entry tail (idx >= 81920, ~2%
// of taps, never tap0) is read from the global planar table, exec-masked.
// __launch_bounds__(1024, 8) caps VGPRs at 64 so both WGs stay resident.

#define LQ   17
#define L2C  (17 * 17)        // 289
#define L3C  (17 * 17 * 17)   // 4913
#define NENT (L3C * 17)       // 83521
#define PLANE_STRIDE 83584    // padded plane stride (multiple of 16)
#define LDS_ENTRIES 81920     // 80 KiB -> 2 WGs/CU
#define LDS_BYTES   81920
#define SUMSTRIDE (L3C + L2C + LQ + 1)  // 5220 (constant full-path offset)

__device__ __forceinline__ int stride_of(int j) {
    // strides[j] = 17^(3-j); cndmask chain, no runtime-indexed array
    return j == 0 ? L3C : (j == 1 ? L2C : (j == 2 ? LQ : 1));
}

// ---- stage 1: quantize weights into 3 channel-planar int8 tables ----
__global__ __launch_bounds__(256) void quant_planar_kernel(
    const float* __restrict__ w, char* __restrict__ planes, int n) {
    int e = blockIdx.x * 256 + threadIdx.x;
    if (e >= n) return;
#pragma unroll
    for (int ch = 0; ch < 3; ++ch) {
        int q = (int)rintf(w[e * 3 + ch] * 127.0f);  // round-half-even
        q = min(127, max(-127, q));
        planes[ch * PLANE_STRIDE + e] = (char)q;
    }
}

// ---- main fused kernel: 512 WGs x 1024 threads, 4 px/thread ----
extern __shared__ char lut[];

__global__ __launch_bounds__(1024, 8) void interp_fused_kernel(
    const float* __restrict__ img, const char* __restrict__ planes,
    float* __restrict__ out) {
    int G = blockIdx.x * 1024 + threadIdx.x;   // group id, 4 px each
    int x0 = (G & 127) << 2;                   // 0..508 step 4
    int y  = (G >> 7) & 511;
    int im = G >> 16;                          // 0..7

    // ---- phase 0: img load + sort ONCE per pixel; cache state in VGPRs ----
    const float* r0 = img + im * (513 * 513) + y * 513 + x0;
    const float* r1 = r0 + 513;
    float v0[5], v1[5];
#pragma unroll
    for (int i = 0; i < 5; ++i) { v0[i] = r0[i]; v1[i] = r1[i]; }

    int pi0[4], pi1[4], pi2[4], pi3[4], pfs[4];
#pragma unroll
    for (int i = 0; i < 4; ++i) {
        int a = (int)v0[i], b = (int)v0[i + 1];
        int c = (int)v1[i], d = (int)v1[i + 1];
        int base = (a >> 4) * L3C + (b >> 4) * L2C + (c >> 4) * LQ + (d >> 4);
        // keys: f*4 + coord_index (replicates argsort(-tie_key))
        int k0 = ((a & 15) << 2) | 0;
        int k1 = ((b & 15) << 2) | 1;
        int k2 = ((c & 15) << 2) | 2;
        int k3 = ((d & 15) << 2) | 3;
        int t;
        if (k0 < k1) { t = k0; k0 = k1; k1 = t; }
        if (k2 < k3) { t = k2; k2 = k3; k3 = t; }
        if (k0 < k2) { t = k0; k0 = k2; k2 = t; }
        if (k1 < k3) { t = k1; k1 = k3; k3 = t; }
        if (k1 < k2) { t = k1; k1 = k2; k2 = t; }
        int fs0 = k0 >> 2, fs1 = k1 >> 2, fs2 = k2 >> 2, fs3 = k3 >> 2;
        int s0 = stride_of(k0 & 3);
        int s1 = stride_of(k1 & 3);
        int s2 = stride_of(k2 & 3);
        pi0[i] = base;                    // <= 78300, always LDS-resident
        pi1[i] = base + s0;
        pi2[i] = base + s0 + s1;
        pi3[i] = base + s0 + s1 + s2;
        pfs[i] = (fs0 << 12) | (fs1 << 8) | (fs2 << 4) | fs3;
    }

    // ---- phases 1..3: per channel, refill LDS plane, gather + dot ----
    float res[12];
#pragma unroll
    for (int ch = 0; ch < 3; ++ch) {
        __syncthreads();   // prior phase's gathers done before overwrite
        {   // fill LDS with first 80 KiB of channel plane (coalesced uint4)
            const uint4* src =
                (const uint4*)(planes + (size_t)ch * PLANE_STRIDE);
            uint4* dst = (uint4*)lut;
            for (int k = threadIdx.x; k < LDS_ENTRIES / 16; k += 1024)
                dst[k] = src[k];
        }
        __syncthreads();
        const signed char* t8 = (const signed char*)lut;
        const signed char* gp =
            (const signed char*)planes + (size_t)ch * PLANE_STRIDE;
#pragma unroll
        for (int i = 0; i < 4; ++i) {
            int fs = pfs[i];
            int fs0 = (fs >> 12) & 15, fs1 = (fs >> 8) & 15;
            int fs2 = (fs >> 4) & 15,  fs3 = fs & 15;
            int i1 = pi1[i], i2 = pi2[i], i3 = pi3[i];
            int i4 = pi0[i] + SUMSTRIDE;
            int p0 = t8[pi0[i]];   // never tail
            // taps 1..4: ~2% of lanes fall in the 1,586-entry tail; the
            // global load issues exec-masked with few active lanes (cheap).
            int p1 = (i1 < LDS_ENTRIES) ? t8[i1] : gp[i1];
            int p2 = (i2 < LDS_ENTRIES) ? t8[i2] : gp[i2];
            int p3 = (i3 < LDS_ENTRIES) ? t8[i3] : gp[i3];
            int p4 = (i4 < LDS_ENTRIES) ? t8[i4] : gp[i4];
            int acc = (16 - fs0) * p0 + (fs0 - fs1) * p1 + (fs1 - fs2) * p2 +
                      (fs2 - fs3) * p3 + fs3 * p4;
            res[i * 3 + ch] = (float)acc * 0.0625f;  // /16 exact
        }
    }

    // ---- single coalesced store: full 64B lines, output written once ----
    int opix = ((im * 512 + y) * 512 + x0) * 3;  // multiple of 12 -> 48B align
    float4* o = (float4*)(out + opix);
    o[0] = make_float4(res[0], res[1], res[2], res[3]);
    o[1] = make_float4(res[4], res[5], res[6], res[7]);
    o[2] = make_float4(res[8], res[9], res[10], res[11]);
}

// ---- fallback path (round-1, proven): packed u32 table, 5 gathers ----
__global__ __launch_bounds__(256) void quant_pack_kernel(
    const float* __restrict__ w, uint32_t* __restrict__ tab, int n) {
    int e = blockIdx.x * 256 + threadIdx.x;
    if (e >= n) return;
    int q0 = (int)rintf(w[e * 3 + 0] * 127.0f);
    int q1 = (int)rintf(w[e * 3 + 1] * 127.0f);
    int q2 = (int)rintf(w[e * 3 + 2] * 127.0f);
    q0 = min(127, max(-127, q0));
    q1 = min(127, max(-127, q1));
    q2 = min(127, max(-127, q2));
    tab[e] = (uint32_t)(q0 & 0xFF) | ((uint32_t)(q1 & 0xFF) << 8) |
             ((uint32_t)(q2 & 0xFF) << 16);
}

__global__ __launch_bounds__(256) void interp_packed_kernel(
    const float* __restrict__ img, const uint32_t* __restrict__ tab,
    float* __restrict__ out) {
    int gid = blockIdx.x * 256 + threadIdx.x;
    int x0 = (gid & 127) << 2;
    int y  = (gid >> 7) & 511;
    int im = gid >> 16;

    const float* r0 = img + im * (513 * 513) + y * 513 + x0;
    const float* r1 = r0 + 513;
    float v0[5], v1[5];
#pragma unroll
    for (int i = 0; i < 5; ++i) { v0[i] = r0[i]; v1[i] = r1[i]; }

    float res[12];
#pragma unroll
    for (int i = 0; i < 4; ++i) {
        int a = (int)v0[i], b = (int)v0[i + 1];
        int c = (int)v1[i], d = (int)v1[i + 1];
        int base = (a >> 4) * L3C + (b >> 4) * L2C + (c >> 4) * LQ + (d >> 4);
        int k0 = ((a & 15) << 2) | 0;
        int k1 = ((b & 15) << 2) | 1;
        int k2 = ((c & 15) << 2) | 2;
        int k3 = ((d & 15) << 2) | 3;
        int t;
        if (k0 < k1) { t = k0; k0 = k1; k1 = t; }
        if (k2 < k3) { t = k2; k2 = k3; k3 = t; }
        if (k0 < k2) { t = k0; k0 = k2; k2 = t; }
        if (k1 < k3) { t = k1; k1 = k3; k3 = t; }
        if (k1 < k2) { t = k1; k1 = k2; k2 = t; }
        int fs0 = k0 >> 2, fs1 = k1 >> 2, fs2 = k2 >> 2, fs3 = k3 >> 2;
        int s0 = stride_of(k0 & 3);
        int s1 = stride_of(k1 & 3);
        int s2 = stride_of(k2 & 3);
        int i0 = base;
        int i1 = base + s0;
        int i2 = i1 + s1;
        int i3 = i2 + s2;
        int i4 = base + SUMSTRIDE;
        uint32_t u0 = tab[i0], u1 = tab[i1], u2 = tab[i2], u3 = tab[i3],
                 u4 = tab[i4];
        int w0 = 16 - fs0, w1 = fs0 - fs1, w2 = fs1 - fs2, w3 = fs2 - fs3,
            w4 = fs3;
#pragma unroll
        for (int chn = 0; chn < 3; ++chn) {
            int sh = 24 - chn * 8;
            int p0 = (int)(u0 << sh) >> 24;
            int p1 = (int)(u1 << sh) >> 24;
            int p2 = (int)(u2 << sh) >> 24;
            int p3 = (int)(u3 << sh) >> 24;
            int p4 = (int)(u4 << sh) >> 24;
            int acc = w0 * p0 + w1 * p1 + w2 * p2 + w3 * p3 + w4 * p4;
            res[i * 3 + chn] = (float)acc * 0.0625f;
        }
    }

    int opix = ((im * 512 + y) * 512 + x0) * 3;
    float4* o = (float4*)(out + opix);
    o[0] = make_float4(res[0], res[1], res[2], res[3]);
    o[1] = make_float4(res[4], res[5], res[6], res[7]);
    o[2] = make_float4(res[8], res[9], res[10], res[11]);
}

extern "C" void kernel_launch(void* const* d_in, const int* in_sizes, int n_in,
                              void* d_out, int out_size, void* d_ws,
                              size_t ws_size, hipStream_t stream) {
    const float* img = (const float*)d_in[0];
    const float* wgt = (const float*)d_in[1];
    float* out = (float*)d_out;

    const size_t planes_bytes = (size_t)3 * PLANE_STRIDE;

    // Enable >64KiB dynamic LDS (host-side attribute, graph-capture safe;
    // proven working rounds 6-8).
    bool lds_ok = (ws_size >= planes_bytes) && (d_ws != nullptr);
    if (lds_ok) {
        hipError_t e = hipFuncSetAttribute(
            reinterpret_cast<const void*>(interp_fused_kernel),
            hipFuncAttributeMaxDynamicSharedMemorySize, LDS_BYTES);
        lds_ok = (e == hipSuccess);
    }

    if (lds_ok) {
        char* planes = (char*)d_ws;    // 3 x 81.6 KiB int8 channel planes
        quant_planar_kernel<<<(NENT + 255) / 256, 256, 0, stream>>>(
            wgt, planes, NENT);
        interp_fused_kernel<<<512, 1024, LDS_BYTES, stream>>>(img, planes,
                                                              out);
    } else if (ws_size >= (size_t)NENT * sizeof(uint32_t) && d_ws != nullptr) {
        uint32_t* tab = (uint32_t*)d_ws;
        quant_pack_kernel<<<(NENT + 255) / 256, 256, 0, stream>>>(wgt, tab,
                                                                  NENT);
        interp_packed_kernel<<<8 * 512 * 128 / 256, 256, 0, stream>>>(
            img, tab, out);
    }
}

// Round 10
// 46.510 us; speedup vs baseline: 1.6995x; 1.6995x over previous
//
#include <hip/hip_runtime.h>
#include <stdint.h>

// SWF2LUT 4-simplex interpolation, mode 's'.
// img_in: (8,1,513,513) f32, integer values 0..255
// weight: (17^4, 3) f32  -> quantized clip(round(w*127),-127,127)
// out:    (8,1,512,512,3) f32
//
// Round-10: round 9 proved 2 WGs/CU is reachable but __launch_bounds__(1024,8)
// capped VGPRs at 64 -> the allocator spilled the cross-barrier state to
// scratch (VGPR_Count=32, FETCH 130MB, WRITE 207MB, 78us). Same occupancy
// WITHOUT the register squeeze: 512-thread WGs, __launch_bounds__(512,4)
// -> 2 WGs x 80KiB LDS = 160KiB, 16 waves/CU, VGPR cap 128 (state ~70, no
// spill). Independent WGs overlap fill/barrier phases with gather phases.

#define LQ   17
#define L2C  (17 * 17)        // 289
#define L3C  (17 * 17 * 17)   // 4913
#define NENT (L3C * 17)       // 83521
#define PLANE_STRIDE 83584    // padded plane stride (multiple of 16)
#define LDS_ENTRIES 81920     // 80 KiB -> 2 WGs/CU
#define LDS_BYTES   81920
#define SUMSTRIDE (L3C + L2C + LQ + 1)  // 5220 (constant full-path offset)

__device__ __forceinline__ int stride_of(int j) {
    // strides[j] = 17^(3-j); cndmask chain, no runtime-indexed array
    return j == 0 ? L3C : (j == 1 ? L2C : (j == 2 ? LQ : 1));
}

// ---- stage 1: quantize weights into 3 channel-planar int8 tables ----
__global__ __launch_bounds__(256) void quant_planar_kernel(
    const float* __restrict__ w, char* __restrict__ planes, int n) {
    int e = blockIdx.x * 256 + threadIdx.x;
    if (e >= n) return;
#pragma unroll
    for (int ch = 0; ch < 3; ++ch) {
        int q = (int)rintf(w[e * 3 + ch] * 127.0f);  // round-half-even
        q = min(127, max(-127, q));
        planes[ch * PLANE_STRIDE + e] = (char)q;
    }
}

// ---- main fused kernel: 1024 WGs x 512 threads, 4 px/thread ----
extern __shared__ char lut[];

__global__ __launch_bounds__(512, 4) void interp_fused_kernel(
    const float* __restrict__ img, const char* __restrict__ planes,
    float* __restrict__ out) {
    int G = blockIdx.x * 512 + threadIdx.x;    // group id, 4 px each
    int x0 = (G & 127) << 2;                   // 0..508 step 4
    int y  = (G >> 7) & 511;
    int im = G >> 16;                          // 0..7

    // ---- phase 0: img load + sort ONCE per pixel; cache state in VGPRs ----
    const float* r0 = img + im * (513 * 513) + y * 513 + x0;
    const float* r1 = r0 + 513;
    float v0[5], v1[5];
#pragma unroll
    for (int i = 0; i < 5; ++i) { v0[i] = r0[i]; v1[i] = r1[i]; }

    int pi0[4], pi1[4], pi2[4], pi3[4], pfs[4];
#pragma unroll
    for (int i = 0; i < 4; ++i) {
        int a = (int)v0[i], b = (int)v0[i + 1];
        int c = (int)v1[i], d = (int)v1[i + 1];
        int base = (a >> 4) * L3C + (b >> 4) * L2C + (c >> 4) * LQ + (d >> 4);
        // keys: f*4 + coord_index (replicates argsort(-tie_key))
        int k0 = ((a & 15) << 2) | 0;
        int k1 = ((b & 15) << 2) | 1;
        int k2 = ((c & 15) << 2) | 2;
        int k3 = ((d & 15) << 2) | 3;
        int t;
        if (k0 < k1) { t = k0; k0 = k1; k1 = t; }
        if (k2 < k3) { t = k2; k2 = k3; k3 = t; }
        if (k0 < k2) { t = k0; k0 = k2; k2 = t; }
        if (k1 < k3) { t = k1; k1 = k3; k3 = t; }
        if (k1 < k2) { t = k1; k1 = k2; k2 = t; }
        int fs0 = k0 >> 2, fs1 = k1 >> 2, fs2 = k2 >> 2, fs3 = k3 >> 2;
        int s0 = stride_of(k0 & 3);
        int s1 = stride_of(k1 & 3);
        int s2 = stride_of(k2 & 3);
        pi0[i] = base;                    // <= 78300, always LDS-resident
        pi1[i] = base + s0;
        pi2[i] = base + s0 + s1;
        pi3[i] = base + s0 + s1 + s2;
        pfs[i] = (fs0 << 12) | (fs1 << 8) | (fs2 << 4) | fs3;
    }

    // ---- phases 1..3: per channel, refill LDS plane, gather + dot ----
    float res[12];
#pragma unroll
    for (int ch = 0; ch < 3; ++ch) {
        __syncthreads();   // prior phase's gathers done before overwrite
        {   // fill LDS with first 80 KiB of channel plane (coalesced uint4)
            const uint4* src =
                (const uint4*)(planes + (size_t)ch * PLANE_STRIDE);
            uint4* dst = (uint4*)lut;
            for (int k = threadIdx.x; k < LDS_ENTRIES / 16; k += 512)
                dst[k] = src[k];
        }
        __syncthreads();
        const signed char* t8 = (const signed char*)lut;
        const signed char* gp =
            (const signed char*)planes + (size_t)ch * PLANE_STRIDE;
#pragma unroll
        for (int i = 0; i < 4; ++i) {
            int fs = pfs[i];
            int fs0 = (fs >> 12) & 15, fs1 = (fs >> 8) & 15;
            int fs2 = (fs >> 4) & 15,  fs3 = fs & 15;
            int i1 = pi1[i], i2 = pi2[i], i3 = pi3[i];
            int i4 = pi0[i] + SUMSTRIDE;
            int p0 = t8[pi0[i]];   // never tail
            // taps 1..4: ~2% of lanes fall in the 1,586-entry tail; the
            // global load issues exec-masked with few active lanes (cheap).
            int p1 = (i1 < LDS_ENTRIES) ? t8[i1] : gp[i1];
            int p2 = (i2 < LDS_ENTRIES) ? t8[i2] : gp[i2];
            int p3 = (i3 < LDS_ENTRIES) ? t8[i3] : gp[i3];
            int p4 = (i4 < LDS_ENTRIES) ? t8[i4] : gp[i4];
            int acc = (16 - fs0) * p0 + (fs0 - fs1) * p1 + (fs1 - fs2) * p2 +
                      (fs2 - fs3) * p3 + fs3 * p4;
            res[i * 3 + ch] = (float)acc * 0.0625f;  // /16 exact
        }
    }

    // ---- single coalesced store: full 64B lines, output written once ----
    int opix = ((im * 512 + y) * 512 + x0) * 3;  // multiple of 12 -> 48B align
    float4* o = (float4*)(out + opix);
    o[0] = make_float4(res[0], res[1], res[2], res[3]);
    o[1] = make_float4(res[4], res[5], res[6], res[7]);
    o[2] = make_float4(res[8], res[9], res[10], res[11]);
}

// ---- fallback path (round-1, proven): packed u32 table, 5 gathers ----
__global__ __launch_bounds__(256) void quant_pack_kernel(
    const float* __restrict__ w, uint32_t* __restrict__ tab, int n) {
    int e = blockIdx.x * 256 + threadIdx.x;
    if (e >= n) return;
    int q0 = (int)rintf(w[e * 3 + 0] * 127.0f);
    int q1 = (int)rintf(w[e * 3 + 1] * 127.0f);
    int q2 = (int)rintf(w[e * 3 + 2] * 127.0f);
    q0 = min(127, max(-127, q0));
    q1 = min(127, max(-127, q1));
    q2 = min(127, max(-127, q2));
    tab[e] = (uint32_t)(q0 & 0xFF) | ((uint32_t)(q1 & 0xFF) << 8) |
             ((uint32_t)(q2 & 0xFF) << 16);
}

__global__ __launch_bounds__(256) void interp_packed_kernel(
    const float* __restrict__ img, const uint32_t* __restrict__ tab,
    float* __restrict__ out) {
    int gid = blockIdx.x * 256 + threadIdx.x;
    int x0 = (gid & 127) << 2;
    int y  = (gid >> 7) & 511;
    int im = gid >> 16;

    const float* r0 = img + im * (513 * 513) + y * 513 + x0;
    const float* r1 = r0 + 513;
    float v0[5], v1[5];
#pragma unroll
    for (int i = 0; i < 5; ++i) { v0[i] = r0[i]; v1[i] = r1[i]; }

    float res[12];
#pragma unroll
    for (int i = 0; i < 4; ++i) {
        int a = (int)v0[i], b = (int)v0[i + 1];
        int c = (int)v1[i], d = (int)v1[i + 1];
        int base = (a >> 4) * L3C + (b >> 4) * L2C + (c >> 4) * LQ + (d >> 4);
        int k0 = ((a & 15) << 2) | 0;
        int k1 = ((b & 15) << 2) | 1;
        int k2 = ((c & 15) << 2) | 2;
        int k3 = ((d & 15) << 2) | 3;
        int t;
        if (k0 < k1) { t = k0; k0 = k1; k1 = t; }
        if (k2 < k3) { t = k2; k2 = k3; k3 = t; }
        if (k0 < k2) { t = k0; k0 = k2; k2 = t; }
        if (k1 < k3) { t = k1; k1 = k3; k3 = t; }
        if (k1 < k2) { t = k1; k1 = k2; k2 = t; }
        int fs0 = k0 >> 2, fs1 = k1 >> 2, fs2 = k2 >> 2, fs3 = k3 >> 2;
        int s0 = stride_of(k0 & 3);
        int s1 = stride_of(k1 & 3);
        int s2 = stride_of(k2 & 3);
        int i0 = base;
        int i1 = base + s0;
        int i2 = i1 + s1;
        int i3 = i2 + s2;
        int i4 = base + SUMSTRIDE;
        uint32_t u0 = tab[i0], u1 = tab[i1], u2 = tab[i2], u3 = tab[i3],
                 u4 = tab[i4];
        int w0 = 16 - fs0, w1 = fs0 - fs1, w2 = fs1 - fs2, w3 = fs2 - fs3,
            w4 = fs3;
#pragma unroll
        for (int chn = 0; chn < 3; ++chn) {
            int sh = 24 - chn * 8;
            int p0 = (int)(u0 << sh) >> 24;
            int p1 = (int)(u1 << sh) >> 24;
            int p2 = (int)(u2 << sh) >> 24;
            int p3 = (int)(u3 << sh) >> 24;
            int p4 = (int)(u4 << sh) >> 24;
            int acc = w0 * p0 + w1 * p1 + w2 * p2 + w3 * p3 + w4 * p4;
            res[i * 3 + chn] = (float)acc * 0.0625f;
        }
    }

    int opix = ((im * 512 + y) * 512 + x0) * 3;
    float4* o = (float4*)(out + opix);
    o[0] = make_float4(res[0], res[1], res[2], res[3]);
    o[1] = make_float4(res[4], res[5], res[6], res[7]);
    o[2] = make_float4(res[8], res[9], res[10], res[11]);
}

extern "C" void kernel_launch(void* const* d_in, const int* in_sizes, int n_in,
                              void* d_out, int out_size, void* d_ws,
                              size_t ws_size, hipStream_t stream) {
    const float* img = (const float*)d_in[0];
    const float* wgt = (const float*)d_in[1];
    float* out = (float*)d_out;

    const size_t planes_bytes = (size_t)3 * PLANE_STRIDE;

    // Enable >64KiB dynamic LDS (host-side attribute, graph-capture safe;
    // proven working rounds 6-9).
    bool lds_ok = (ws_size >= planes_bytes) && (d_ws != nullptr);
    if (lds_ok) {
        hipError_t e = hipFuncSetAttribute(
            reinterpret_cast<const void*>(interp_fused_kernel),
            hipFuncAttributeMaxDynamicSharedMemorySize, LDS_BYTES);
        lds_ok = (e == hipSuccess);
    }

    if (lds_ok) {
        char* planes = (char*)d_ws;    // 3 x 81.6 KiB int8 channel planes
        quant_planar_kernel<<<(NENT + 255) / 256, 256, 0, stream>>>(
            wgt, planes, NENT);
        interp_fused_kernel<<<1024, 512, LDS_BYTES, stream>>>(img, planes,
                                                              out);
    } else if (ws_size >= (size_t)NENT * sizeof(uint32_t) && d_ws != nullptr) {
        uint32_t* tab = (uint32_t*)d_ws;
        quant_pack_kernel<<<(NENT + 255) / 256, 256, 0, stream>>>(wgt, tab,
                                                                  NENT);
        interp_packed_kernel<<<8 * 512 * 128 / 256, 256, 0, stream>>>(
            img, tab, out);
    }
}

// Round 11
// 36.426 us; speedup vs baseline: 2.1700x; 1.2768x over previous
//
#include <hip/hip_runtime.h>
#include <stdint.h>

// SWF2LUT 4-simplex interpolation, mode 's'.
// img_in: (8,1,513,513) f32, integer values 0..255
// weight: (17^4, 3) f32  -> quantized clip(round(w*127),-127,127)
// out:    (8,1,512,512,3) f32
//
// Round-11: fill cost scales with WG count (each WG fills the whole plane).
// Round 8 = 501 KiB fill/CU (26.5us); round 10 = 960 KiB/CU (41.4us) ->
// fill ~0.033us/KiB/CU dominates. This round: 256 WGs x 1024 thr x 8 px =
// ONE WG per CU, one generation -> 250 KiB fill/CU, full plane in LDS (no
// tail predicates). Per-px state bit-packed to ~3 regs so the 1024-thread
// WG stays under the 128-VGPR ceiling (round 9's spill lesson).

#define LQ   17
#define L2C  (17 * 17)        // 289
#define L3C  (17 * 17 * 17)   // 4913
#define NENT (L3C * 17)       // 83521
#define PLANE_STRIDE 83584    // padded plane stride (multiple of 16)
#define LDS_BYTES   83584
#define SUMSTRIDE (L3C + L2C + LQ + 1)  // 5220 (constant full-path offset)

__device__ __forceinline__ int stride_of(int j) {
    // strides[j] = 17^(3-j); cndmask chain, no runtime-indexed array
    return j == 0 ? L3C : (j == 1 ? L2C : (j == 2 ? LQ : 1));
}

// ---- stage 1: quantize weights into 3 channel-planar int8 tables ----
__global__ __launch_bounds__(256) void quant_planar_kernel(
    const float* __restrict__ w, char* __restrict__ planes, int n) {
    int e = blockIdx.x * 256 + threadIdx.x;
    if (e >= n) return;
#pragma unroll
    for (int ch = 0; ch < 3; ++ch) {
        int q = (int)rintf(w[e * 3 + ch] * 127.0f);  // round-half-even
        q = min(127, max(-127, q));
        planes[ch * PLANE_STRIDE + e] = (char)q;
    }
}

// ---- main fused kernel: 256 WGs x 1024 threads, 8 px/thread ----
extern __shared__ char lut[];

__global__ __launch_bounds__(1024) void interp_fused_kernel(
    const float* __restrict__ img, const char* __restrict__ planes,
    float* __restrict__ out) {
    int G = blockIdx.x * 1024 + threadIdx.x;   // 0..262143, 8 px each
    int x0 = (G & 63) << 3;                    // 0..504 step 8
    int y  = (G >> 6) & 511;
    int im = G >> 15;                          // 0..7

    // ---- phase 0: img load + sort ONCE per pixel; packed state in VGPRs ---
    const float* r0 = img + im * (513 * 513) + y * 513 + x0;
    const float* r1 = r0 + 513;
    float v0[9], v1[9];
#pragma unroll
    for (int i = 0; i < 9; ++i) { v0[i] = r0[i]; v1[i] = r1[i]; }

    // per-px packed state: pi0 (17b), pk1 = o1 | o2<<13, pk2 = fs | o3<<16
    int pi0[8], pk1[8], pk2[8];
#pragma unroll
    for (int i = 0; i < 8; ++i) {
        int a = (int)v0[i], b = (int)v0[i + 1];
        int c = (int)v1[i], d = (int)v1[i + 1];
        int base = (a >> 4) * L3C + (b >> 4) * L2C + (c >> 4) * LQ + (d >> 4);
        // keys: f*4 + coord_index (replicates argsort(-tie_key))
        int k0 = ((a & 15) << 2) | 0;
        int k1 = ((b & 15) << 2) | 1;
        int k2 = ((c & 15) << 2) | 2;
        int k3 = ((d & 15) << 2) | 3;
        int t;
        if (k0 < k1) { t = k0; k0 = k1; k1 = t; }
        if (k2 < k3) { t = k2; k2 = k3; k3 = t; }
        if (k0 < k2) { t = k0; k0 = k2; k2 = t; }
        if (k1 < k3) { t = k1; k1 = k3; k3 = t; }
        if (k1 < k2) { t = k1; k1 = k2; k2 = t; }
        int fs0 = k0 >> 2, fs1 = k1 >> 2, fs2 = k2 >> 2, fs3 = k3 >> 2;
        int s0 = stride_of(k0 & 3);               // o1 <= 4913 (13 bits)
        int s01 = s0 + stride_of(k1 & 3);         // o2 <= 5202 (13 bits)
        int s012 = s01 + stride_of(k2 & 3);       // o3 <= 5219 (13 bits)
        pi0[i] = base;
        pk1[i] = s0 | (s01 << 13);
        pk2[i] = (fs0 << 12) | (fs1 << 8) | (fs2 << 4) | fs3 | (s012 << 16);
    }

    // channel accumulators, 2 px per reg (acc in [-2032,2032] fits int16)
    int racc[3][4];
#pragma unroll
    for (int ch = 0; ch < 3; ++ch)
#pragma unroll
        for (int p = 0; p < 4; ++p) racc[ch][p] = 0;

    // ---- phases 1..3: per channel, fill LDS plane, gather + dot ----
#pragma unroll
    for (int ch = 0; ch < 3; ++ch) {
        __syncthreads();   // prior phase's gathers done before overwrite
        {   // fill LDS with channel plane (coalesced uint4 copies)
            const uint4* src =
                (const uint4*)(planes + (size_t)ch * PLANE_STRIDE);
            uint4* dst = (uint4*)lut;
            for (int k = threadIdx.x; k < PLANE_STRIDE / 16; k += 1024)
                dst[k] = src[k];
        }
        __syncthreads();
        const signed char* t8 = (const signed char*)lut;
#pragma unroll
        for (int i = 0; i < 8; ++i) {
            int fs = pk2[i];
            int fs0 = (fs >> 12) & 15, fs1 = (fs >> 8) & 15;
            int fs2 = (fs >> 4) & 15,  fs3 = fs & 15;
            int i0 = pi0[i];
            int i1 = i0 + (pk1[i] & 0x1FFF);
            int i2 = i0 + (pk1[i] >> 13);
            int i3 = i0 + ((fs >> 16) & 0x1FFF);
            int i4 = i0 + SUMSTRIDE;
            int p0 = t8[i0];   // all 5 taps LDS-resident (max idx 83505)
            int p1 = t8[i1];
            int p2 = t8[i2];
            int p3 = t8[i3];
            int p4 = t8[i4];
            int acc = (16 - fs0) * p0 + (fs0 - fs1) * p1 + (fs1 - fs2) * p2 +
                      (fs2 - fs3) * p3 + fs3 * p4;
            racc[ch][i >> 1] |= (acc & 0xFFFF) << (16 * (i & 1));
        }
    }

    // ---- unpack + single coalesced store (6 float4, output written once) --
    float res[24];
#pragma unroll
    for (int ch = 0; ch < 3; ++ch)
#pragma unroll
        for (int p = 0; p < 4; ++p) {
            int lo = (racc[ch][p] << 16) >> 16;   // px 2p
            int hi = racc[ch][p] >> 16;           // px 2p+1
            res[(2 * p) * 3 + ch]     = (float)lo * 0.0625f;  // /16 exact
            res[(2 * p + 1) * 3 + ch] = (float)hi * 0.0625f;
        }

    int opix = ((im * 512 + y) * 512 + x0) * 3;  // x0 mult of 8 -> 96B chunks
    float4* o = (float4*)(out + opix);
#pragma unroll
    for (int q = 0; q < 6; ++q)
        o[q] = make_float4(res[q * 4], res[q * 4 + 1], res[q * 4 + 2],
                           res[q * 4 + 3]);
}

// ---- fallback path (round-1, proven): packed u32 table, 5 gathers ----
__global__ __launch_bounds__(256) void quant_pack_kernel(
    const float* __restrict__ w, uint32_t* __restrict__ tab, int n) {
    int e = blockIdx.x * 256 + threadIdx.x;
    if (e >= n) return;
    int q0 = (int)rintf(w[e * 3 + 0] * 127.0f);
    int q1 = (int)rintf(w[e * 3 + 1] * 127.0f);
    int q2 = (int)rintf(w[e * 3 + 2] * 127.0f);
    q0 = min(127, max(-127, q0));
    q1 = min(127, max(-127, q1));
    q2 = min(127, max(-127, q2));
    tab[e] = (uint32_t)(q0 & 0xFF) | ((uint32_t)(q1 & 0xFF) << 8) |
             ((uint32_t)(q2 & 0xFF) << 16);
}

__global__ __launch_bounds__(256) void interp_packed_kernel(
    const float* __restrict__ img, const uint32_t* __restrict__ tab,
    float* __restrict__ out) {
    int gid = blockIdx.x * 256 + threadIdx.x;
    int x0 = (gid & 127) << 2;
    int y  = (gid >> 7) & 511;
    int im = gid >> 16;

    const float* r0 = img + im * (513 * 513) + y * 513 + x0;
    const float* r1 = r0 + 513;
    float v0[5], v1[5];
#pragma unroll
    for (int i = 0; i < 5; ++i) { v0[i] = r0[i]; v1[i] = r1[i]; }

    float res[12];
#pragma unroll
    for (int i = 0; i < 4; ++i) {
        int a = (int)v0[i], b = (int)v0[i + 1];
        int c = (int)v1[i], d = (int)v1[i + 1];
        int base = (a >> 4) * L3C + (b >> 4) * L2C + (c >> 4) * LQ + (d >> 4);
        int k0 = ((a & 15) << 2) | 0;
        int k1 = ((b & 15) << 2) | 1;
        int k2 = ((c & 15) << 2) | 2;
        int k3 = ((d & 15) << 2) | 3;
        int t;
        if (k0 < k1) { t = k0; k0 = k1; k1 = t; }
        if (k2 < k3) { t = k2; k2 = k3; k3 = t; }
        if (k0 < k2) { t = k0; k0 = k2; k2 = t; }
        if (k1 < k3) { t = k1; k1 = k3; k3 = t; }
        if (k1 < k2) { t = k1; k1 = k2; k2 = t; }
        int fs0 = k0 >> 2, fs1 = k1 >> 2, fs2 = k2 >> 2, fs3 = k3 >> 2;
        int s0 = stride_of(k0 & 3);
        int s1 = stride_of(k1 & 3);
        int s2 = stride_of(k2 & 3);
        int i0 = base;
        int i1 = base + s0;
        int i2 = i1 + s1;
        int i3 = i2 + s2;
        int i4 = base + SUMSTRIDE;
        uint32_t u0 = tab[i0], u1 = tab[i1], u2 = tab[i2], u3 = tab[i3],
                 u4 = tab[i4];
        int w0 = 16 - fs0, w1 = fs0 - fs1, w2 = fs1 - fs2, w3 = fs2 - fs3,
            w4 = fs3;
#pragma unroll
        for (int chn = 0; chn < 3; ++chn) {
            int sh = 24 - chn * 8;
            int p0 = (int)(u0 << sh) >> 24;
            int p1 = (int)(u1 << sh) >> 24;
            int p2 = (int)(u2 << sh) >> 24;
            int p3 = (int)(u3 << sh) >> 24;
            int p4 = (int)(u4 << sh) >> 24;
            int acc = w0 * p0 + w1 * p1 + w2 * p2 + w3 * p3 + w4 * p4;
            res[i * 3 + chn] = (float)acc * 0.0625f;
        }
    }

    int opix = ((im * 512 + y) * 512 + x0) * 3;
    float4* o = (float4*)(out + opix);
    o[0] = make_float4(res[0], res[1], res[2], res[3]);
    o[1] = make_float4(res[4], res[5], res[6], res[7]);
    o[2] = make_float4(res[8], res[9], res[10], res[11]);
}

extern "C" void kernel_launch(void* const* d_in, const int* in_sizes, int n_in,
                              void* d_out, int out_size, void* d_ws,
                              size_t ws_size, hipStream_t stream) {
    const float* img = (const float*)d_in[0];
    const float* wgt = (const float*)d_in[1];
    float* out = (float*)d_out;

    const size_t planes_bytes = (size_t)3 * PLANE_STRIDE;

    // Enable >64KiB dynamic LDS (host-side attribute, graph-capture safe;
    // proven working rounds 6-10).
    bool lds_ok = (ws_size >= planes_bytes) && (d_ws != nullptr);
    if (lds_ok) {
        hipError_t e = hipFuncSetAttribute(
            reinterpret_cast<const void*>(interp_fused_kernel),
            hipFuncAttributeMaxDynamicSharedMemorySize, LDS_BYTES);
        lds_ok = (e == hipSuccess);
    }

    if (lds_ok) {
        char* planes = (char*)d_ws;    // 3 x 81.6 KiB int8 channel planes
        quant_planar_kernel<<<(NENT + 255) / 256, 256, 0, stream>>>(
            wgt, planes, NENT);
        interp_fused_kernel<<<256, 1024, LDS_BYTES, stream>>>(img, planes,
                                                              out);
    } else if (ws_size >= (size_t)NENT * sizeof(uint32_t) && d_ws != nullptr) {
        uint32_t* tab = (uint32_t*)d_ws;
        quant_pack_kernel<<<(NENT + 255) / 256, 256, 0, stream>>>(wgt, tab,
                                                                  NENT);
        interp_packed_kernel<<<8 * 512 * 128 / 256, 256, 0, stream>>>(
            img, tab, out);
    }
}